// Round 11
// baseline (112.993 us; speedup 1.0000x reference)
//
#include <hip/hip_runtime.h>
#include <hip/hip_bf16.h>

typedef __attribute__((ext_vector_type(8))) short short8;
typedef __attribute__((ext_vector_type(4))) float f32x4;

// ---- ws: p_flat (409600 f32) then per-zone pre-swizzled bf16 slab ----
// slab (bytes, per zone, = LDS image [0,44032)):
//   Wih [192][16B] linear @0 (3072); Whh swz @3072 (24576);
//   W1 swz @27648 (8192); W2 swz @35840 (8192).  SLAB = 44032.
// swz: byte(row, pair j) = row*128 + ((j*4) ^ ((row&7)<<4))
#define SLAB 44032
#define WS_W_OFF 1638400

// ---- actor LDS (bytes): weights image; X; H; A. total 117760 ----
#define OFF_X 44032      // [2t][256b][16B] = 8192
#define OFF_H 52224      // [8w][32b][128B swz] = 32768
#define OFF_A 84992      // 32768 -> 117760
#define LDS_TOTAL 117760

__device__ __forceinline__ unsigned pkbf(float a, float b) {
    __hip_bfloat162 h = __float22bfloat162_rn(make_float2(a, b));  // v_cvt_pk_bf16_f32
    return *reinterpret_cast<unsigned*>(&h);
}
__device__ __forceinline__ float sigf(float x) {
    return __builtin_amdgcn_rcpf(1.f + __builtin_amdgcn_exp2f(-1.4426950408889634f * x));
}
__device__ __forceinline__ float tanhfast(float y) {
    return 1.f - 2.f * __builtin_amdgcn_rcpf(1.f + __builtin_amdgcn_exp2f(2.8853900817779268f * y));
}
__device__ __forceinline__ void g2l16(const void* g, void* l) {
    __builtin_amdgcn_global_load_lds(
        (const __attribute__((address_space(1))) void*)g,
        (__attribute__((address_space(3))) void*)l, 16, 0, 0);
}

// ---------------------------------------------------------------------------
// Pre-pass: build pre-swizzled bf16 slabs (exact LDS image) in ws.
// ---------------------------------------------------------------------------
__global__ __launch_bounds__(256)
void convert_kernel(const float* __restrict__ Wih, const float* __restrict__ Whh,
                    const float* __restrict__ W1, const float* __restrict__ W2,
                    char* __restrict__ slab)
{
    int idx = blockIdx.x * 256 + threadIdx.x;
    if (idx >= 100 * 11008) return;
    int n = idx / 11008;
    int i = idx - n * 11008;
    char* zs = slab + (size_t)n * SLAB;
    if (i < 768) {                                   // Wih linear [192][16B]
        int row = i >> 2, j = i & 3;
        const float* g = Wih + n * 1152 + row * 6;
        float a = (2 * j < 6) ? g[2 * j] : 0.f;
        float b = (2 * j + 1 < 6) ? g[2 * j + 1] : 0.f;
        *(unsigned*)(zs + row * 16 + j * 4) = pkbf(a, b);
    } else if (i < 6912) {                           // Whh swz
        int k = i - 768, row = k >> 5, j = k & 31;
        float2 v = *(const float2*)(Whh + n * 12288 + row * 64 + j * 2);
        *(unsigned*)(zs + 3072 + row * 128 + ((j * 4) ^ ((row & 7) << 4))) = pkbf(v.x, v.y);
    } else if (i < 8960) {                           // W1 swz
        int k = i - 6912, row = k >> 5, j = k & 31;
        float2 v = *(const float2*)(W1 + n * 4096 + row * 64 + j * 2);
        *(unsigned*)(zs + 27648 + row * 128 + ((j * 4) ^ ((row & 7) << 4))) = pkbf(v.x, v.y);
    } else {                                         // W2 swz
        int k = i - 8960, row = k >> 5, j = k & 31;
        float2 v = *(const float2*)(W2 + n * 4096 + row * 64 + j * 2);
        *(unsigned*)(zs + 35840 + row * 128 + ((j * 4) ^ ((row & 7) << 4))) = pkbf(v.x, v.y);
    }
}

// ---------------------------------------------------------------------------
// Actor: grid 800 = 100 zones x 8 chunks(256 batches), block 512 = 8 waves.
// Wave owns 32 batches = 2 N-subtiles of 16 (2 ILP streams). 44 KB weight
// image shared by 8 waves (amortized 2x vs R10); 117.8 KB LDS -> 1 block/CU,
// 8 waves/CU = 2/SIMD guaranteed. One __syncthreads.
// C/D: col=lane&15 (batch), row=(lane>>4)*4+reg (channel)  [m89-verified].
// p written ONLY to p_flat (n,b,t)-major; p[:, -1] gather stays in critic.
// ---------------------------------------------------------------------------
__global__ __launch_bounds__(512, 2)
void actor_kernel(const float* __restrict__ x, const char* __restrict__ slab,
                  const float* __restrict__ bih, const float* __restrict__ bhh,
                  const float* __restrict__ b1, const float* __restrict__ b2,
                  const float* __restrict__ W3, const float* __restrict__ b3,
                  float* __restrict__ p_flat)
{
    extern __shared__ char sm[];
    const int tid   = threadIdx.x;
    const int n     = blockIdx.x >> 3;
    const int chunk = blockIdx.x & 7;
    const int w     = tid >> 6;
    const int l     = tid & 63;
    const int bcol  = l & 15;
    const int grp   = l >> 4;
    const int a7    = bcol & 7;
    const int ch0   = grp * 4;

    // ---- staging: weights via async global->LDS (43 KB, linear image) ----
    {
        const char* gz = slab + (size_t)n * SLAB;
        for (int i = w; i < 43; i += 8)
            g2l16(gz + i * 1024 + l * 16, sm + i * 1024);
        // x: 512 rows (t,b), 6 f32 -> 8 bf16
        int t = tid >> 8, b = tid & 255;
        const float* xr = x + (size_t)(chunk * 256 + b) * 1200 + t * 600 + n * 6;
        uint4 pk;
        pk.x = pkbf(xr[0], xr[1]);
        pk.y = pkbf(xr[2], xr[3]);
        pk.z = pkbf(xr[4], xr[5]);
        pk.w = 0u;
        *(uint4*)(sm + OFF_X + (t * 256 + b) * 16) = pk;
    }
    __syncthreads();   // drains vmcnt (global_load_lds) + lgkmcnt

    // ---- swizzled bases ----
    const int gsz = (grp ^ a7) << 4;
    const char* wihp = sm + bcol * 16;                       // + tile*256
    const char* whhA = sm + 3072  + bcol * 128 + gsz;        // + gtile*2048
    const char* whhB = sm + 3072  + bcol * 128 + (gsz ^ 64);
    const char* w1A  = sm + 27648 + bcol * 128 + gsz;
    const char* w1B  = sm + 27648 + bcol * 128 + (gsz ^ 64);
    const char* w2A  = sm + 35840 + bcol * 128 + gsz;
    const char* w2B  = sm + 35840 + bcol * 128 + (gsz ^ 64);
    char* hTile = sm + OFF_H + w * 4096;                     // [32b][128B]
    char* aTile = sm + OFF_A + w * 4096;
    const int wgr = (grp & 1) * 8;
    const int g1v = grp >> 1;

    // ---- hoisted biases (persistent regs) ----
    const float* bihz = bih + n * 192;
    const float* bhhz = bhh + n * 192;
    f32x4 bRi[4], bZi[4], bXNi[4], bHNi[4];
#pragma unroll
    for (int mt = 0; mt < 4; ++mt) {
        const int ch = mt * 16 + ch0;
        bRi[mt]  = *(const f32x4*)&bihz[ch]      + *(const f32x4*)&bhhz[ch];
        bZi[mt]  = *(const f32x4*)&bihz[64 + ch] + *(const f32x4*)&bhhz[64 + ch];
        bXNi[mt] = *(const f32x4*)&bihz[128 + ch];
        bHNi[mt] = *(const f32x4*)&bhhz[128 + ch];
    }
    const float b3v = b3[n];
    const short8 zfrag = {0, 0, 0, 0, 0, 0, 0, 0};

    f32x4 hp[2][4];
#pragma unroll
    for (int nt = 0; nt < 2; ++nt)
#pragma unroll
        for (int mt = 0; mt < 4; ++mt) hp[nt][mt] = (f32x4){0.f, 0.f, 0.f, 0.f};

    for (int t = 0; t < 2; ++t) {
        short8 bxv[2] = {zfrag, zfrag};
        if (grp == 0) {
            bxv[0] = *(const short8*)(sm + OFF_X + (t * 256 + w * 32 + bcol) * 16);
            bxv[1] = *(const short8*)(sm + OFF_X + (t * 256 + w * 32 + 16 + bcol) * 16);
        }
        short8 bh0v[2], bh1v[2];
        if (t == 1) {
#pragma unroll
            for (int nt = 0; nt < 2; ++nt) {
                bh0v[nt] = *(const short8*)(hTile + (nt * 16 + bcol) * 128 + gsz);
                bh1v[nt] = *(const short8*)(hTile + (nt * 16 + bcol) * 128 + (gsz ^ 64));
            }
        }
        // ---- GRU gates + cell, per M-tile, 2 subtile streams ----
#pragma unroll
        for (int mt = 0; mt < 4; ++mt) {
            f32x4 aR[2], aZ[2], aXN[2], aHN[2];
#pragma unroll
            for (int nt = 0; nt < 2; ++nt) {
                aR[nt] = bRi[mt]; aZ[nt] = bZi[mt]; aXN[nt] = bXNi[mt]; aHN[nt] = bHNi[mt];
            }
            short8 wr = zfrag, wzg = zfrag, wn = zfrag;
            if (grp == 0) {
                wr  = *(const short8*)(wihp + (0 + mt) * 256);
                wzg = *(const short8*)(wihp + (4 + mt) * 256);
                wn  = *(const short8*)(wihp + (8 + mt) * 256);
            }
#pragma unroll
            for (int nt = 0; nt < 2; ++nt) {
                aR[nt]  = __builtin_amdgcn_mfma_f32_16x16x32_bf16(wr,  bxv[nt], aR[nt],  0, 0, 0);
                aZ[nt]  = __builtin_amdgcn_mfma_f32_16x16x32_bf16(wzg, bxv[nt], aZ[nt],  0, 0, 0);
                aXN[nt] = __builtin_amdgcn_mfma_f32_16x16x32_bf16(wn,  bxv[nt], aXN[nt], 0, 0, 0);
            }
            if (t == 1) {
                short8 r0 = *(const short8*)(whhA + (0 + mt) * 2048);
                short8 r1 = *(const short8*)(whhB + (0 + mt) * 2048);
                short8 z0 = *(const short8*)(whhA + (4 + mt) * 2048);
                short8 z1 = *(const short8*)(whhB + (4 + mt) * 2048);
                short8 n0 = *(const short8*)(whhA + (8 + mt) * 2048);
                short8 n1 = *(const short8*)(whhB + (8 + mt) * 2048);
#pragma unroll
                for (int nt = 0; nt < 2; ++nt) {
                    aR[nt]  = __builtin_amdgcn_mfma_f32_16x16x32_bf16(r0, bh0v[nt], aR[nt],  0, 0, 0);
                    aR[nt]  = __builtin_amdgcn_mfma_f32_16x16x32_bf16(r1, bh1v[nt], aR[nt],  0, 0, 0);
                    aZ[nt]  = __builtin_amdgcn_mfma_f32_16x16x32_bf16(z0, bh0v[nt], aZ[nt],  0, 0, 0);
                    aZ[nt]  = __builtin_amdgcn_mfma_f32_16x16x32_bf16(z1, bh1v[nt], aZ[nt],  0, 0, 0);
                    aHN[nt] = __builtin_amdgcn_mfma_f32_16x16x32_bf16(n0, bh0v[nt], aHN[nt], 0, 0, 0);
                    aHN[nt] = __builtin_amdgcn_mfma_f32_16x16x32_bf16(n1, bh1v[nt], aHN[nt], 0, 0, 0);
                }
            }
#pragma unroll
            for (int nt = 0; nt < 2; ++nt) {
                f32x4 h2;
#pragma unroll
                for (int r = 0; r < 4; ++r) {
                    float rg = sigf(aR[nt][r]);
                    float zg = sigf(aZ[nt][r]);
                    float nn = tanhfast(aXN[nt][r] + rg * aHN[nt][r]);
                    h2[r] = nn + zg * (hp[nt][mt][r] - nn);
                }
                hp[nt][mt] = h2;
                char* wmt = hTile + nt * 2048 + bcol * 128 + wgr + (((2 * mt + g1v) ^ a7) << 4);
                if (t == 0) {
                    uint2 ph; ph.x = pkbf(h2[0], h2[1]); ph.y = pkbf(h2[2], h2[3]);
                    *(uint2*)wmt = ph;
                }
                uint2 pa;
                pa.x = pkbf(fmaxf(h2[0], 0.f), fmaxf(h2[1], 0.f));
                pa.y = pkbf(fmaxf(h2[2], 0.f), fmaxf(h2[3], 0.f));
                *(uint2*)(wmt + 32768) = pa;    // A tile = H tile + 32768
            }
        }
        // ---- MLP layer 1 ----
        {
            short8 ba0[2], ba1[2];
#pragma unroll
            for (int nt = 0; nt < 2; ++nt) {
                ba0[nt] = *(const short8*)(aTile + (nt * 16 + bcol) * 128 + gsz);
                ba1[nt] = *(const short8*)(aTile + (nt * 16 + bcol) * 128 + (gsz ^ 64));
            }
#pragma unroll
            for (int mt = 0; mt < 4; ++mt) {
                short8 wa  = *(const short8*)(w1A + mt * 2048);
                short8 wbv = *(const short8*)(w1B + mt * 2048);
                f32x4 bmv = *(const f32x4*)&b1[n * 64 + mt * 16 + ch0];
#pragma unroll
                for (int nt = 0; nt < 2; ++nt) {
                    f32x4 m1 = bmv;
                    m1 = __builtin_amdgcn_mfma_f32_16x16x32_bf16(wa,  ba0[nt], m1, 0, 0, 0);
                    m1 = __builtin_amdgcn_mfma_f32_16x16x32_bf16(wbv, ba1[nt], m1, 0, 0, 0);
                    uint2 pm;
                    pm.x = pkbf(fmaxf(m1[0], 0.f), fmaxf(m1[1], 0.f));
                    pm.y = pkbf(fmaxf(m1[2], 0.f), fmaxf(m1[3], 0.f));
                    *(uint2*)(aTile + nt * 2048 + bcol * 128 + wgr + (((2 * mt + g1v) ^ a7) << 4)) = pm;
                }
            }
        }
        // ---- MLP layer 2 + head ----
        {
            short8 bm0[2], bm1[2];
#pragma unroll
            for (int nt = 0; nt < 2; ++nt) {
                bm0[nt] = *(const short8*)(aTile + (nt * 16 + bcol) * 128 + gsz);
                bm1[nt] = *(const short8*)(aTile + (nt * 16 + bcol) * 128 + (gsz ^ 64));
            }
            float part[2] = {0.f, 0.f};
#pragma unroll
            for (int mt = 0; mt < 4; ++mt) {
                short8 wa  = *(const short8*)(w2A + mt * 2048);
                short8 wbv = *(const short8*)(w2B + mt * 2048);
                f32x4 bmv = *(const f32x4*)&b2[n * 64 + mt * 16 + ch0];
                f32x4 w3v = *(const f32x4*)&W3[n * 64 + mt * 16 + ch0];
#pragma unroll
                for (int nt = 0; nt < 2; ++nt) {
                    f32x4 m2 = bmv;
                    m2 = __builtin_amdgcn_mfma_f32_16x16x32_bf16(wa,  bm0[nt], m2, 0, 0, 0);
                    m2 = __builtin_amdgcn_mfma_f32_16x16x32_bf16(wbv, bm1[nt], m2, 0, 0, 0);
#pragma unroll
                    for (int r = 0; r < 4; ++r)
                        part[nt] += w3v[r] * fmaxf(m2[r], 0.f);
                }
            }
#pragma unroll
            for (int nt = 0; nt < 2; ++nt) {
                part[nt] += __shfl_xor(part[nt], 16, 64);
                part[nt] += __shfl_xor(part[nt], 32, 64);
            }
            if (l < 16) {
#pragma unroll
                for (int nt = 0; nt < 2; ++nt) {
                    int bg = chunk * 256 + w * 32 + nt * 16 + bcol;
                    float val = 3.f * (sigf(part[nt] + b3v) - 0.5f);
                    p_flat[n * 4096 + bg * 2 + t] = val;     // (n,b,t)-major
                }
            }
        }
    }
}

// ---------------------------------------------------------------------------
// Critic + p-last gather: grid 128, block 256 = 4 waves, wave owns 4 batch
// rows (weight loads amortized 4x -> L2 traffic /4). All LDS rows are
// wave-private -> only one __syncthreads (xi build).
// Only zone 99 contributes; neighbors {99,89,0,0,98}.
// p[b,t,nn] = p_flat_FLAT[b*200 + t*100 + nn]  (flat reinterpretation).
// ---------------------------------------------------------------------------
__global__ __launch_bounds__(256, 2)
void critic_kernel(const float* __restrict__ x, const float* __restrict__ p_flat,
                   const float* __restrict__ lmW1, const float* __restrict__ lmb1,
                   const float* __restrict__ lmW2, const float* __restrict__ lmb2,
                   const float* __restrict__ lmW3, const float* __restrict__ lmb3,
                   const float* __restrict__ scWih, const float* __restrict__ scWhh,
                   const float* __restrict__ scbih, const float* __restrict__ scbhh,
                   const float* __restrict__ scW1, const float* __restrict__ scb1,
                   const float* __restrict__ scW2, const float* __restrict__ scb2,
                   const float* __restrict__ scW3, const float* __restrict__ scb3,
                   float* __restrict__ out)
{
    __shared__ float sxi[16][72];
    __shared__ float shh[16][68];
    __shared__ float sab[16][68];
    __shared__ float sc1[16][68];
    __shared__ float sf1[16][132];

    const int tid = threadIdx.x;
    const int wid = tid >> 6;
    const int lane = tid & 63;
    const int b0 = blockIdx.x * 16 + wid * 4;   // 4 rows per wave

    for (int idx = lane; idx < 288; idx += 64) {
        int r = idx / 72, k = idx - r * 72;
        int t = k / 36, c = k - t * 36;
        float v = 0.f;
        if (c < 35) {
            int g = c / 7, e = c - g * 7;
            int z = (g == 0) ? 99 : (g == 1) ? 89 : (g == 4) ? 98 : -1;
            if (z >= 0)
                v = (e < 6) ? x[((size_t)(b0 + r) * 2 + t) * 600 + z * 6 + e]
                            : p_flat[(b0 + r) * 200 + t * 100 + z];
        }
        sxi[wid * 4 + r][k] = v;
    }
    __syncthreads();   // only barrier; everything below is wave-private rows

    // ---- cgx for 4 rows, both t ----
    const float bir = scbih[lane], biz = scbih[lane + 64], bin = scbih[lane + 128];
    float cr0[4], cz0[4], cn0[4], cr1[4], cz1[4], cn1[4];
#pragma unroll
    for (int r = 0; r < 4; ++r) {
        cr0[r] = bir; cz0[r] = biz; cn0[r] = bin;
        cr1[r] = bir; cz1[r] = biz; cn1[r] = bin;
    }
    for (int c = 0; c < 35; ++c) {
        float w0 = scWih[lane * 35 + c];
        float w1 = scWih[(lane + 64) * 35 + c];
        float w2 = scWih[(lane + 128) * 35 + c];
#pragma unroll
        for (int r = 0; r < 4; ++r) {
            float x0 = sxi[wid * 4 + r][c], x1 = sxi[wid * 4 + r][36 + c];
            cr0[r] += w0 * x0; cz0[r] += w1 * x0; cn0[r] += w2 * x0;
            cr1[r] += w0 * x1; cz1[r] += w1 * x1; cn1[r] += w2 * x1;
        }
    }
    const float bhr = scbhh[lane], bhz = scbhh[lane + 64], bhn = scbhh[lane + 128];
    // ---- t=0 cell (h=0) ----
    float hj[4];
#pragma unroll
    for (int r = 0; r < 4; ++r) {
        float rg = 1.f / (1.f + expf(-(cr0[r] + bhr)));
        float zg = 1.f / (1.f + expf(-(cz0[r] + bhz)));
        float nn = tanhf(cn0[r] + rg * bhn);
        hj[r] = (1.f - zg) * nn;
        shh[wid * 4 + r][lane] = hj[r];
    }
    // ---- t=1: gh = Whh . h ----
    float ghr[4], ghz[4], ghn[4];
#pragma unroll
    for (int r = 0; r < 4; ++r) { ghr[r] = bhr; ghz[r] = bhz; ghn[r] = bhn; }
    for (int kc = 0; kc < 16; ++kc) {
        float4 wr  = *(const float4*)&scWhh[lane * 64 + kc * 4];
        float4 wzv = *(const float4*)&scWhh[(lane + 64) * 64 + kc * 4];
        float4 wn  = *(const float4*)&scWhh[(lane + 128) * 64 + kc * 4];
#pragma unroll
        for (int r = 0; r < 4; ++r) {
            float4 hv = *(const float4*)&shh[wid * 4 + r][kc * 4];
            ghr[r] += wr.x * hv.x + wr.y * hv.y + wr.z * hv.z + wr.w * hv.w;
            ghz[r] += wzv.x * hv.x + wzv.y * hv.y + wzv.z * hv.z + wzv.w * hv.w;
            ghn[r] += wn.x * hv.x + wn.y * hv.y + wn.z * hv.z + wn.w * hv.w;
        }
    }
#pragma unroll
    for (int r = 0; r < 4; ++r) {
        float rg = 1.f / (1.f + expf(-(cr1[r] + ghr[r])));
        float zg = 1.f / (1.f + expf(-(cz1[r] + ghz[r])));
        float nn = tanhf(cn1[r] + rg * ghn[r]);
        hj[r] = (1.f - zg) * nn + zg * hj[r];
        sab[wid * 4 + r][lane] = fmaxf(hj[r], 0.f);
    }
    // ---- sc MLP layer 1 ----
    float acc[4];
#pragma unroll
    for (int r = 0; r < 4; ++r) acc[r] = scb1[lane];
    for (int kc = 0; kc < 16; ++kc) {
        float4 wv = *(const float4*)&scW1[lane * 64 + kc * 4];
#pragma unroll
        for (int r = 0; r < 4; ++r) {
            float4 av = *(const float4*)&sab[wid * 4 + r][kc * 4];
            acc[r] += wv.x * av.x + wv.y * av.y + wv.z * av.z + wv.w * av.w;
        }
    }
#pragma unroll
    for (int r = 0; r < 4; ++r) sc1[wid * 4 + r][lane] = fmaxf(acc[r], 0.f);
    // ---- sc MLP layer 2 + W3 ----
    float qpart[4];
#pragma unroll
    for (int r = 0; r < 4; ++r) acc[r] = scb2[lane];
    for (int kc = 0; kc < 16; ++kc) {
        float4 wv = *(const float4*)&scW2[lane * 64 + kc * 4];
#pragma unroll
        for (int r = 0; r < 4; ++r) {
            float4 av = *(const float4*)&sc1[wid * 4 + r][kc * 4];
            acc[r] += wv.x * av.x + wv.y * av.y + wv.z * av.z + wv.w * av.w;
        }
    }
    const float w3l = scW3[lane];
#pragma unroll
    for (int r = 0; r < 4; ++r) qpart[r] = w3l * fmaxf(acc[r], 0.f);
    // ---- localized module on xi[t=1] ----
    float f1a[4], f1c[4];
#pragma unroll
    for (int r = 0; r < 4; ++r) { f1a[r] = lmb1[lane]; f1c[r] = lmb1[lane + 64]; }
    for (int c = 0; c < 35; ++c) {
        float wa = lmW1[lane * 35 + c];
        float wc = lmW1[(lane + 64) * 35 + c];
#pragma unroll
        for (int r = 0; r < 4; ++r) {
            float xv = sxi[wid * 4 + r][36 + c];
            f1a[r] += wa * xv;
            f1c[r] += wc * xv;
        }
    }
#pragma unroll
    for (int r = 0; r < 4; ++r) {
        sf1[wid * 4 + r][lane] = fmaxf(f1a[r], 0.f);
        sf1[wid * 4 + r][lane + 64] = fmaxf(f1c[r], 0.f);
    }
    float f2a[4], f2c[4];
#pragma unroll
    for (int r = 0; r < 4; ++r) { f2a[r] = lmb2[lane]; f2c[r] = lmb2[lane + 64]; }
    for (int kc = 0; kc < 32; ++kc) {
        float4 wa = *(const float4*)&lmW2[lane * 128 + kc * 4];
        float4 wc = *(const float4*)&lmW2[(lane + 64) * 128 + kc * 4];
#pragma unroll
        for (int r = 0; r < 4; ++r) {
            float4 fv = *(const float4*)&sf1[wid * 4 + r][kc * 4];
            f2a[r] += wa.x * fv.x + wa.y * fv.y + wa.z * fv.z + wa.w * fv.w;
            f2c[r] += wc.x * fv.x + wc.y * fv.y + wc.z * fv.z + wc.w * fv.w;
        }
    }
    const float w3a = lmW3[lane], w3c = lmW3[lane + 64];
#pragma unroll
    for (int r = 0; r < 4; ++r) {
        float tot = qpart[r] + w3a * fmaxf(f2a[r], 0.f) + w3c * fmaxf(f2c[r], 0.f);
        for (int m = 32; m > 0; m >>= 1) tot += __shfl_xor(tot, m, 64);
        if (lane == 0) out[204800 + b0 + r] = tot + scb3[0] + lmb3[0];
    }

    // p[:, -1] gather: out[b*100 + l2] = flat[b*200 + 100 + l2]
#pragma unroll
    for (int r = 0; r < 4; ++r)
        for (int l2 = lane; l2 < 100; l2 += 64)
            out[(b0 + r) * 100 + l2] = p_flat[(b0 + r) * 200 + 100 + l2];
}

extern "C" void kernel_launch(void* const* d_in, const int* in_sizes, int n_in,
                              void* d_out, int out_size, void* d_ws, size_t ws_size,
                              hipStream_t stream) {
    const float* x     = (const float*)d_in[0];
    const float* aWih  = (const float*)d_in[1];
    const float* aWhh  = (const float*)d_in[2];
    const float* abih  = (const float*)d_in[3];
    const float* abhh  = (const float*)d_in[4];
    const float* aW1   = (const float*)d_in[5];
    const float* ab1   = (const float*)d_in[6];
    const float* aW2   = (const float*)d_in[7];
    const float* ab2   = (const float*)d_in[8];
    const float* aW3   = (const float*)d_in[9];
    const float* ab3   = (const float*)d_in[10];
    const float* lmW1  = (const float*)d_in[11];
    const float* lmb1  = (const float*)d_in[12];
    const float* lmW2  = (const float*)d_in[13];
    const float* lmb2  = (const float*)d_in[14];
    const float* lmW3  = (const float*)d_in[15];
    const float* lmb3  = (const float*)d_in[16];
    const float* scWih = (const float*)d_in[17];
    const float* scWhh = (const float*)d_in[18];
    const float* scbih = (const float*)d_in[19];
    const float* scbhh = (const float*)d_in[20];
    const float* scW1  = (const float*)d_in[21];
    const float* scb1  = (const float*)d_in[22];
    const float* scW2  = (const float*)d_in[23];
    const float* scb2  = (const float*)d_in[24];
    const float* scW3  = (const float*)d_in[25];
    const float* scb3  = (const float*)d_in[26];
    float* out = (float*)d_out;
    float* p_flat = (float*)d_ws;                        // 1.6 MB
    char* slab = (char*)d_ws + WS_W_OFF;                 // 4.4 MB

    hipFuncSetAttribute((const void*)actor_kernel,
                        hipFuncAttributeMaxDynamicSharedMemorySize, LDS_TOTAL);

    convert_kernel<<<dim3((100 * 11008 + 255) / 256), 256, 0, stream>>>(
        aWih, aWhh, aW1, aW2, slab);

    actor_kernel<<<dim3(800), 512, LDS_TOTAL, stream>>>(
        x, slab, abih, abhh, ab1, ab2, aW3, ab3, p_flat);

    critic_kernel<<<dim3(128), 256, 0, stream>>>(
        x, p_flat, lmW1, lmb1, lmW2, lmb2, lmW3, lmb3,
        scWih, scWhh, scbih, scbhh, scW1, scb1, scW2, scb2, scW3, scb3, out);
}

// Round 12
// 78.199 us; speedup vs baseline: 1.4449x; 1.4449x over previous
//
#include <hip/hip_runtime.h>
#include <hip/hip_bf16.h>

typedef __attribute__((ext_vector_type(8))) short short8;
typedef __attribute__((ext_vector_type(4))) float f32x4;

// ---- ws layout ----
// p_flat: 409600 f32 @0 (1638400 B)
// slab:   per-zone pre-swizzled bf16 LDS image @WS_W_OFF, SLAB bytes/zone
// cw:     fp32 TRANSPOSED critic weights @WS_CW_OFF (48064 floats):
//   tWih [35][192] @0; tWhh [64][192] @6720; tW1 [64][64] @19008;
//   tW2 @23104; tlm1 [35][128] @27200; tlm2 [128][128] @31680; end 48064.
#define SLAB 44032
#define WS_W_OFF 1638400
#define WS_CW_OFF (WS_W_OFF + 100 * SLAB)
#define E_SLAB 1100800   // slab dwords (100 * 11008)
#define E_CW   48064     // critic transposed floats

// ---- actor LDS (bytes): weights image [0,44032); X; H; A. total 80896 ----
#define OFF_X 44032      // [2t][128b][16B] = 4096
#define OFF_H 48128      // [4w][32b][128B swz] = 16384
#define OFF_A 64512      // 16384 -> 80896
#define LDS_TOTAL 80896

__device__ __forceinline__ unsigned pkbf(float a, float b) {
    __hip_bfloat162 h = __float22bfloat162_rn(make_float2(a, b));  // v_cvt_pk_bf16_f32
    return *reinterpret_cast<unsigned*>(&h);
}
__device__ __forceinline__ float sigf(float x) {
    return __builtin_amdgcn_rcpf(1.f + __builtin_amdgcn_exp2f(-1.4426950408889634f * x));
}
__device__ __forceinline__ float tanhfast(float y) {
    return 1.f - 2.f * __builtin_amdgcn_rcpf(1.f + __builtin_amdgcn_exp2f(2.8853900817779268f * y));
}
__device__ __forceinline__ void g2l16(const void* g, void* l) {
    __builtin_amdgcn_global_load_lds(
        (const __attribute__((address_space(1))) void*)g,
        (__attribute__((address_space(3))) void*)l, 16, 0, 0);
}

// ---------------------------------------------------------------------------
// Pre-pass: (a) pre-swizzled bf16 actor slabs; (b) fp32 transposed critic
// weights (coalesced-read layout). One thread per output element.
// ---------------------------------------------------------------------------
__global__ __launch_bounds__(256)
void convert_kernel(const float* __restrict__ Wih, const float* __restrict__ Whh,
                    const float* __restrict__ W1, const float* __restrict__ W2,
                    const float* __restrict__ scWih, const float* __restrict__ scWhh,
                    const float* __restrict__ scW1, const float* __restrict__ scW2,
                    const float* __restrict__ lmW1, const float* __restrict__ lmW2,
                    char* __restrict__ slab, float* __restrict__ cw)
{
    int idx = blockIdx.x * 256 + threadIdx.x;
    if (idx < E_SLAB) {
        int n = idx / 11008;
        int i = idx - n * 11008;
        char* zs = slab + (size_t)n * SLAB;
        if (i < 768) {                                   // Wih linear [192][16B]
            int row = i >> 2, j = i & 3;
            const float* g = Wih + n * 1152 + row * 6;
            float a = (2 * j < 6) ? g[2 * j] : 0.f;
            float b = (2 * j + 1 < 6) ? g[2 * j + 1] : 0.f;
            *(unsigned*)(zs + row * 16 + j * 4) = pkbf(a, b);
        } else if (i < 6912) {                           // Whh swz
            int k = i - 768, row = k >> 5, j = k & 31;
            float2 v = *(const float2*)(Whh + n * 12288 + row * 64 + j * 2);
            *(unsigned*)(zs + 3072 + row * 128 + ((j * 4) ^ ((row & 7) << 4))) = pkbf(v.x, v.y);
        } else if (i < 8960) {                           // W1 swz
            int k = i - 6912, row = k >> 5, j = k & 31;
            float2 v = *(const float2*)(W1 + n * 4096 + row * 64 + j * 2);
            *(unsigned*)(zs + 27648 + row * 128 + ((j * 4) ^ ((row & 7) << 4))) = pkbf(v.x, v.y);
        } else {                                         // W2 swz
            int k = i - 8960, row = k >> 5, j = k & 31;
            float2 v = *(const float2*)(W2 + n * 4096 + row * 64 + j * 2);
            *(unsigned*)(zs + 35840 + row * 128 + ((j * 4) ^ ((row & 7) << 4))) = pkbf(v.x, v.y);
        }
        return;
    }
    int i = idx - E_SLAB;
    if (i >= E_CW) return;
    float v;
    if (i < 6720)        { int c = i / 192,          j = i - c * 192;          v = scWih[j * 35 + c]; }
    else if (i < 19008)  { int k = (i - 6720) / 192, j = (i - 6720) - k * 192; v = scWhh[j * 64 + k]; }
    else if (i < 23104)  { int k = (i - 19008) / 64, j = (i - 19008) - k * 64; v = scW1[j * 64 + k]; }
    else if (i < 27200)  { int k = (i - 23104) / 64, j = (i - 23104) - k * 64; v = scW2[j * 64 + k]; }
    else if (i < 31680)  { int c = (i - 27200) / 128, j = (i - 27200) - c * 128; v = lmW1[j * 35 + c]; }
    else                 { int k = (i - 31680) / 128, j = (i - 31680) - k * 128; v = lmW2[j * 128 + k]; }
    cw[i] = v;
}

// ---------------------------------------------------------------------------
// Actor (R10-proven): grid 1600 = 100 zones x 16 chunks(128 batches),
// block 256 = 4 waves, wave owns 32 batches = 2 N-subtiles (2 ILP streams).
// Weights via global_load_lds from pre-swizzled slab; 80896 B LDS -> 2
// blocks/CU. One __syncthreads.
// C/D: col=lane&15 (batch), row=(lane>>4)*4+reg (channel)  [m89-verified].
// ---------------------------------------------------------------------------
__global__ __launch_bounds__(256, 2)
void actor_kernel(const float* __restrict__ x, const char* __restrict__ slab,
                  const float* __restrict__ bih, const float* __restrict__ bhh,
                  const float* __restrict__ b1, const float* __restrict__ b2,
                  const float* __restrict__ W3, const float* __restrict__ b3,
                  float* __restrict__ p_flat)
{
    extern __shared__ char sm[];
    const int tid   = threadIdx.x;
    const int n     = blockIdx.x >> 4;
    const int chunk = blockIdx.x & 15;
    const int w     = tid >> 6;
    const int l     = tid & 63;
    const int bcol  = l & 15;
    const int grp   = l >> 4;
    const int a7    = bcol & 7;
    const int ch0   = grp * 4;

    // ---- staging: weights via async global->LDS (43 KB, linear image) ----
    {
        const char* gz = slab + (size_t)n * SLAB;
        for (int i = w; i < 43; i += 4)
            g2l16(gz + i * 1024 + l * 16, sm + i * 1024);
        int t = tid >> 7, b = tid & 127;
        const float* xr = x + (size_t)(chunk * 128 + b) * 1200 + t * 600 + n * 6;
        uint4 pk;
        pk.x = pkbf(xr[0], xr[1]);
        pk.y = pkbf(xr[2], xr[3]);
        pk.z = pkbf(xr[4], xr[5]);
        pk.w = 0u;
        *(uint4*)(sm + OFF_X + (t * 128 + b) * 16) = pk;
    }
    __syncthreads();

    const int gsz = (grp ^ a7) << 4;
    const char* wihp = sm + bcol * 16;
    const char* whhA = sm + 3072  + bcol * 128 + gsz;
    const char* whhB = sm + 3072  + bcol * 128 + (gsz ^ 64);
    const char* w1A  = sm + 27648 + bcol * 128 + gsz;
    const char* w1B  = sm + 27648 + bcol * 128 + (gsz ^ 64);
    const char* w2A  = sm + 35840 + bcol * 128 + gsz;
    const char* w2B  = sm + 35840 + bcol * 128 + (gsz ^ 64);
    char* hTile = sm + OFF_H + w * 4096;
    char* aTile = sm + OFF_A + w * 4096;
    const int wgr = (grp & 1) * 8;
    const int g1v = grp >> 1;

    const float* bihz = bih + n * 192;
    const float* bhhz = bhh + n * 192;
    f32x4 bRi[4], bZi[4], bXNi[4], bHNi[4];
#pragma unroll
    for (int mt = 0; mt < 4; ++mt) {
        const int ch = mt * 16 + ch0;
        bRi[mt]  = *(const f32x4*)&bihz[ch]      + *(const f32x4*)&bhhz[ch];
        bZi[mt]  = *(const f32x4*)&bihz[64 + ch] + *(const f32x4*)&bhhz[64 + ch];
        bXNi[mt] = *(const f32x4*)&bihz[128 + ch];
        bHNi[mt] = *(const f32x4*)&bhhz[128 + ch];
    }
    const float b3v = b3[n];
    const short8 zfrag = {0, 0, 0, 0, 0, 0, 0, 0};

    f32x4 hp[2][4];
#pragma unroll
    for (int nt = 0; nt < 2; ++nt)
#pragma unroll
        for (int mt = 0; mt < 4; ++mt) hp[nt][mt] = (f32x4){0.f, 0.f, 0.f, 0.f};

    for (int t = 0; t < 2; ++t) {
        short8 bxv[2] = {zfrag, zfrag};
        if (grp == 0) {
            bxv[0] = *(const short8*)(sm + OFF_X + (t * 128 + w * 32 + bcol) * 16);
            bxv[1] = *(const short8*)(sm + OFF_X + (t * 128 + w * 32 + 16 + bcol) * 16);
        }
        short8 bh0v[2], bh1v[2];
        if (t == 1) {
#pragma unroll
            for (int nt = 0; nt < 2; ++nt) {
                bh0v[nt] = *(const short8*)(hTile + (nt * 16 + bcol) * 128 + gsz);
                bh1v[nt] = *(const short8*)(hTile + (nt * 16 + bcol) * 128 + (gsz ^ 64));
            }
        }
#pragma unroll
        for (int mt = 0; mt < 4; ++mt) {
            f32x4 aR[2], aZ[2], aXN[2], aHN[2];
#pragma unroll
            for (int nt = 0; nt < 2; ++nt) {
                aR[nt] = bRi[mt]; aZ[nt] = bZi[mt]; aXN[nt] = bXNi[mt]; aHN[nt] = bHNi[mt];
            }
            short8 wr = zfrag, wzg = zfrag, wn = zfrag;
            if (grp == 0) {
                wr  = *(const short8*)(wihp + (0 + mt) * 256);
                wzg = *(const short8*)(wihp + (4 + mt) * 256);
                wn  = *(const short8*)(wihp + (8 + mt) * 256);
            }
#pragma unroll
            for (int nt = 0; nt < 2; ++nt) {
                aR[nt]  = __builtin_amdgcn_mfma_f32_16x16x32_bf16(wr,  bxv[nt], aR[nt],  0, 0, 0);
                aZ[nt]  = __builtin_amdgcn_mfma_f32_16x16x32_bf16(wzg, bxv[nt], aZ[nt],  0, 0, 0);
                aXN[nt] = __builtin_amdgcn_mfma_f32_16x16x32_bf16(wn,  bxv[nt], aXN[nt], 0, 0, 0);
            }
            if (t == 1) {
                short8 r0 = *(const short8*)(whhA + (0 + mt) * 2048);
                short8 r1 = *(const short8*)(whhB + (0 + mt) * 2048);
                short8 z0 = *(const short8*)(whhA + (4 + mt) * 2048);
                short8 z1 = *(const short8*)(whhB + (4 + mt) * 2048);
                short8 n0 = *(const short8*)(whhA + (8 + mt) * 2048);
                short8 n1 = *(const short8*)(whhB + (8 + mt) * 2048);
#pragma unroll
                for (int nt = 0; nt < 2; ++nt) {
                    aR[nt]  = __builtin_amdgcn_mfma_f32_16x16x32_bf16(r0, bh0v[nt], aR[nt],  0, 0, 0);
                    aR[nt]  = __builtin_amdgcn_mfma_f32_16x16x32_bf16(r1, bh1v[nt], aR[nt],  0, 0, 0);
                    aZ[nt]  = __builtin_amdgcn_mfma_f32_16x16x32_bf16(z0, bh0v[nt], aZ[nt],  0, 0, 0);
                    aZ[nt]  = __builtin_amdgcn_mfma_f32_16x16x32_bf16(z1, bh1v[nt], aZ[nt],  0, 0, 0);
                    aHN[nt] = __builtin_amdgcn_mfma_f32_16x16x32_bf16(n0, bh0v[nt], aHN[nt], 0, 0, 0);
                    aHN[nt] = __builtin_amdgcn_mfma_f32_16x16x32_bf16(n1, bh1v[nt], aHN[nt], 0, 0, 0);
                }
            }
#pragma unroll
            for (int nt = 0; nt < 2; ++nt) {
                f32x4 h2;
#pragma unroll
                for (int r = 0; r < 4; ++r) {
                    float rg = sigf(aR[nt][r]);
                    float zg = sigf(aZ[nt][r]);
                    float nn = tanhfast(aXN[nt][r] + rg * aHN[nt][r]);
                    h2[r] = nn + zg * (hp[nt][mt][r] - nn);
                }
                hp[nt][mt] = h2;
                char* wmt = hTile + nt * 2048 + bcol * 128 + wgr + (((2 * mt + g1v) ^ a7) << 4);
                if (t == 0) {
                    uint2 ph; ph.x = pkbf(h2[0], h2[1]); ph.y = pkbf(h2[2], h2[3]);
                    *(uint2*)wmt = ph;
                }
                uint2 pa;
                pa.x = pkbf(fmaxf(h2[0], 0.f), fmaxf(h2[1], 0.f));
                pa.y = pkbf(fmaxf(h2[2], 0.f), fmaxf(h2[3], 0.f));
                *(uint2*)(wmt + 16384) = pa;
            }
        }
        // ---- MLP layer 1 ----
        {
            short8 ba0[2], ba1[2];
#pragma unroll
            for (int nt = 0; nt < 2; ++nt) {
                ba0[nt] = *(const short8*)(aTile + (nt * 16 + bcol) * 128 + gsz);
                ba1[nt] = *(const short8*)(aTile + (nt * 16 + bcol) * 128 + (gsz ^ 64));
            }
#pragma unroll
            for (int mt = 0; mt < 4; ++mt) {
                short8 wa  = *(const short8*)(w1A + mt * 2048);
                short8 wbv = *(const short8*)(w1B + mt * 2048);
                f32x4 bmv = *(const f32x4*)&b1[n * 64 + mt * 16 + ch0];
#pragma unroll
                for (int nt = 0; nt < 2; ++nt) {
                    f32x4 m1 = bmv;
                    m1 = __builtin_amdgcn_mfma_f32_16x16x32_bf16(wa,  ba0[nt], m1, 0, 0, 0);
                    m1 = __builtin_amdgcn_mfma_f32_16x16x32_bf16(wbv, ba1[nt], m1, 0, 0, 0);
                    uint2 pm;
                    pm.x = pkbf(fmaxf(m1[0], 0.f), fmaxf(m1[1], 0.f));
                    pm.y = pkbf(fmaxf(m1[2], 0.f), fmaxf(m1[3], 0.f));
                    *(uint2*)(aTile + nt * 2048 + bcol * 128 + wgr + (((2 * mt + g1v) ^ a7) << 4)) = pm;
                }
            }
        }
        // ---- MLP layer 2 + head ----
        {
            short8 bm0[2], bm1[2];
#pragma unroll
            for (int nt = 0; nt < 2; ++nt) {
                bm0[nt] = *(const short8*)(aTile + (nt * 16 + bcol) * 128 + gsz);
                bm1[nt] = *(const short8*)(aTile + (nt * 16 + bcol) * 128 + (gsz ^ 64));
            }
            float part[2] = {0.f, 0.f};
#pragma unroll
            for (int mt = 0; mt < 4; ++mt) {
                short8 wa  = *(const short8*)(w2A + mt * 2048);
                short8 wbv = *(const short8*)(w2B + mt * 2048);
                f32x4 bmv = *(const f32x4*)&b2[n * 64 + mt * 16 + ch0];
                f32x4 w3v = *(const f32x4*)&W3[n * 64 + mt * 16 + ch0];
#pragma unroll
                for (int nt = 0; nt < 2; ++nt) {
                    f32x4 m2 = bmv;
                    m2 = __builtin_amdgcn_mfma_f32_16x16x32_bf16(wa,  bm0[nt], m2, 0, 0, 0);
                    m2 = __builtin_amdgcn_mfma_f32_16x16x32_bf16(wbv, bm1[nt], m2, 0, 0, 0);
#pragma unroll
                    for (int r = 0; r < 4; ++r)
                        part[nt] += w3v[r] * fmaxf(m2[r], 0.f);
                }
            }
#pragma unroll
            for (int nt = 0; nt < 2; ++nt) {
                part[nt] += __shfl_xor(part[nt], 16, 64);
                part[nt] += __shfl_xor(part[nt], 32, 64);
            }
            if (l < 16) {
#pragma unroll
                for (int nt = 0; nt < 2; ++nt) {
                    int bg = chunk * 128 + w * 32 + nt * 16 + bcol;
                    float val = 3.f * (sigf(part[nt] + b3v) - 0.5f);
                    p_flat[n * 4096 + bg * 2 + t] = val;     // (n,b,t)-major
                }
            }
        }
    }
}

// ---------------------------------------------------------------------------
// Critic + p-last gather: grid 512, block 256, wave per batch row (R10
// structure) with TRANSPOSED fp32 weights -> every weight load coalesced.
// Only zone 99 contributes; neighbors {99,89,0,0,98}.
// p[b,t,nn] = p_flat_FLAT[b*200 + t*100 + nn]  (flat reinterpretation).
// ---------------------------------------------------------------------------
__global__ __launch_bounds__(256, 2)
void critic_kernel(const float* __restrict__ x, const float* __restrict__ p_flat,
                   const float* __restrict__ cw,
                   const float* __restrict__ lmb1, const float* __restrict__ lmb2,
                   const float* __restrict__ lmW3, const float* __restrict__ lmb3,
                   const float* __restrict__ scbih, const float* __restrict__ scbhh,
                   const float* __restrict__ scb1, const float* __restrict__ scb2,
                   const float* __restrict__ scW3, const float* __restrict__ scb3,
                   float* __restrict__ out)
{
    const float* tWih = cw;            // [35][192]
    const float* tWhh = cw + 6720;     // [64][192]
    const float* tW1  = cw + 19008;    // [64][64]
    const float* tW2  = cw + 23104;    // [64][64]
    const float* tlm1 = cw + 27200;    // [35][128]
    const float* tlm2 = cw + 31680;    // [128][128]

    __shared__ float sxi[4][72];
    __shared__ float shh[4][68];
    __shared__ float sab[4][68];
    __shared__ float sc1[4][68];
    __shared__ float sf1[4][132];

    const int tid = threadIdx.x;
    const int wid = tid >> 6;
    const int lane = tid & 63;
    const int b = blockIdx.x * 4 + wid;

    for (int idx = lane; idx < 72; idx += 64) {
        int t = idx / 36, c = idx - t * 36;
        float v = 0.f;
        if (c < 35) {
            int g = c / 7, e = c - g * 7;
            int z = (g == 0) ? 99 : (g == 1) ? 89 : (g == 4) ? 98 : -1;
            if (z >= 0)
                v = (e < 6) ? x[((size_t)b * 2 + t) * 600 + z * 6 + e]
                            : p_flat[b * 200 + t * 100 + z];
        }
        sxi[wid][idx] = v;
    }
    __syncthreads();

    float cg00 = scbih[lane], cg01 = scbih[lane + 64], cg02 = scbih[lane + 128];
    float cg10 = cg00, cg11 = cg01, cg12 = cg02;
#pragma unroll 5
    for (int c = 0; c < 35; ++c) {
        float w0 = tWih[c * 192 + lane];
        float w1 = tWih[c * 192 + 64 + lane];
        float w2 = tWih[c * 192 + 128 + lane];
        float x0 = sxi[wid][c], x1 = sxi[wid][36 + c];
        cg00 += w0 * x0; cg01 += w1 * x0; cg02 += w2 * x0;
        cg10 += w0 * x1; cg11 += w1 * x1; cg12 += w2 * x1;
    }
    const float bhr = scbhh[lane], bhz = scbhh[lane + 64], bhn = scbhh[lane + 128];
    float r  = 1.f / (1.f + expf(-(cg00 + bhr)));
    float zg = 1.f / (1.f + expf(-(cg01 + bhz)));
    float nn = tanhf(cg02 + r * bhn);
    float hj = (1.f - zg) * nn;
    shh[wid][lane] = hj;
    __syncthreads();
    float ghr = bhr, ghz = bhz, ghn = bhn;
#pragma unroll 8
    for (int k = 0; k < 64; ++k) {
        float hk = shh[wid][k];
        ghr += tWhh[k * 192 + lane] * hk;
        ghz += tWhh[k * 192 + 64 + lane] * hk;
        ghn += tWhh[k * 192 + 128 + lane] * hk;
    }
    r  = 1.f / (1.f + expf(-(cg10 + ghr)));
    zg = 1.f / (1.f + expf(-(cg11 + ghz)));
    nn = tanhf(cg12 + r * ghn);
    hj = (1.f - zg) * nn + zg * hj;
    sab[wid][lane] = fmaxf(hj, 0.f);
    __syncthreads();
    float acc = scb1[lane];
#pragma unroll 8
    for (int k = 0; k < 64; ++k)
        acc += tW1[k * 64 + lane] * sab[wid][k];
    sc1[wid][lane] = fmaxf(acc, 0.f);
    __syncthreads();
    float acc2 = scb2[lane];
#pragma unroll 8
    for (int k = 0; k < 64; ++k)
        acc2 += tW2[k * 64 + lane] * sc1[wid][k];
    float qpart = scW3[lane] * fmaxf(acc2, 0.f);
    float f1a = lmb1[lane], f1c = lmb1[lane + 64];
#pragma unroll 5
    for (int c = 0; c < 35; ++c) {
        float xv = sxi[wid][36 + c];
        f1a += tlm1[c * 128 + lane] * xv;
        f1c += tlm1[c * 128 + 64 + lane] * xv;
    }
    sf1[wid][lane] = fmaxf(f1a, 0.f);
    sf1[wid][lane + 64] = fmaxf(f1c, 0.f);
    __syncthreads();
    float f2a = lmb2[lane], f2c = lmb2[lane + 64];
#pragma unroll 8
    for (int k = 0; k < 128; ++k) {
        float fv = sf1[wid][k];
        f2a += tlm2[k * 128 + lane] * fv;
        f2c += tlm2[k * 128 + 64 + lane] * fv;
    }
    float fpart = lmW3[lane] * fmaxf(f2a, 0.f) + lmW3[lane + 64] * fmaxf(f2c, 0.f);

    float tot = qpart + fpart;
    for (int m = 32; m > 0; m >>= 1) tot += __shfl_xor(tot, m, 64);
    if (lane == 0) out[204800 + b] = tot + scb3[0] + lmb3[0];

    // p[:, -1] gather: out[b*100 + l2] = flat[b*200 + 100 + l2]
    for (int l2 = lane; l2 < 100; l2 += 64)
        out[b * 100 + l2] = p_flat[b * 200 + 100 + l2];
}

extern "C" void kernel_launch(void* const* d_in, const int* in_sizes, int n_in,
                              void* d_out, int out_size, void* d_ws, size_t ws_size,
                              hipStream_t stream) {
    const float* x     = (const float*)d_in[0];
    const float* aWih  = (const float*)d_in[1];
    const float* aWhh  = (const float*)d_in[2];
    const float* abih  = (const float*)d_in[3];
    const float* abhh  = (const float*)d_in[4];
    const float* aW1   = (const float*)d_in[5];
    const float* ab1   = (const float*)d_in[6];
    const float* aW2   = (const float*)d_in[7];
    const float* ab2   = (const float*)d_in[8];
    const float* aW3   = (const float*)d_in[9];
    const float* ab3   = (const float*)d_in[10];
    const float* lmW1  = (const float*)d_in[11];
    const float* lmb1  = (const float*)d_in[12];
    const float* lmW2  = (const float*)d_in[13];
    const float* lmb2  = (const float*)d_in[14];
    const float* lmW3  = (const float*)d_in[15];
    const float* lmb3  = (const float*)d_in[16];
    const float* scWih = (const float*)d_in[17];
    const float* scWhh = (const float*)d_in[18];
    const float* scbih = (const float*)d_in[19];
    const float* scbhh = (const float*)d_in[20];
    const float* scW1  = (const float*)d_in[21];
    const float* scb1  = (const float*)d_in[22];
    const float* scW2  = (const float*)d_in[23];
    const float* scb2  = (const float*)d_in[24];
    const float* scW3  = (const float*)d_in[25];
    const float* scb3  = (const float*)d_in[26];
    float* out = (float*)d_out;
    float* p_flat = (float*)d_ws;                        // 1.6 MB
    char* slab = (char*)d_ws + WS_W_OFF;                 // 4.4 MB
    float* cw  = (float*)((char*)d_ws + WS_CW_OFF);      // 192 KB

    hipFuncSetAttribute((const void*)actor_kernel,
                        hipFuncAttributeMaxDynamicSharedMemorySize, LDS_TOTAL);

    convert_kernel<<<dim3((E_SLAB + E_CW + 255) / 256), 256, 0, stream>>>(
        aWih, aWhh, aW1, aW2, scWih, scWhh, scW1, scW2, lmW1, lmW2, slab, cw);

    actor_kernel<<<dim3(1600), 256, LDS_TOTAL, stream>>>(
        x, slab, abih, abhh, ab1, ab2, aW3, ab3, p_flat);

    critic_kernel<<<dim3(512), 256, 0, stream>>>(
        x, p_flat, cw, lmb1, lmb2, lmW3, lmb3,
        scbih, scbhh, scb1, scb2, scW3, scb3, out);
}